// Round 7
// baseline (129.093 us; speedup 1.0000x reference)
//
#include <hip/hip_runtime.h>
#include <hip/hip_fp16.h>

// BasisFunction2D, round 7: pipelined staging.
// Block = (o-pair, i-pair) -> 512 blocks x 512 threads, double-buffered
// f16-packed LDS (2 x 38.1 KB, 2 blocks/CU = 16 waves/CU).
//   stage i0 -> [issue i1 global loads] gather i0 -> pack/write i1 -> gather i1
// so the HBM staging of slice i1 overlaps the LDS/VALU gather of i0
// (previous rounds were stage-THEN-gather single-generation: phases globally
// serialized, which R4/R6 neutrality proved was the bound).
// zc transposed to [b][j], read as uint4 (2 j per VMEM instr).
// One atomicAdd pair per thread (i0+i1 pre-summed).

#define NG        16
#define NB        17             // NG+1
#define IN_X      32
#define IN_Z      32
#define OUT_DIM   64
#define BATCH     512
#define CELLS     (NB * NB)      // 289
#define LDS_STR   33             // 32 + 1 pad (element units)
#define XSTR      (NB * LDS_STR) // 561
#define QT        (CELLS * 8)    // 2312 quad-tasks per slice
#define NITER     5              // ceil(QT / 512)

__device__ __forceinline__ void grid_coord(float v,
                                           const float* __restrict__ borders,
                                           const float* __restrict__ inv_len,
                                           int& idx, float& w) {
    float e   = expf(-fabsf(v));
    float cdf = (v > 0.f) ? (1.f - 0.5f * e) : (0.5f * e);
    int t = (int)(cdf * 16.f);
    t = t < 0 ? 0 : (t > NG - 1 ? NG - 1 : t);
    idx = t;
    w = (v - borders[t]) * inv_len[t];
}

__device__ __forceinline__ __half2 u2h(unsigned u) {
    union { unsigned u; __half2 h; } v; v.u = u; return v.h;
}
__device__ __forceinline__ unsigned h2u(__half2 h) {
    union { unsigned u; __half2 h; } v; v.h = h; return v.u;
}

// 32768 threads: gid<16384 -> x table, else z table (transposed [b][j]).
// Also zeroes out[] (32768 elements).
__global__ void precompute_kernel(const float* __restrict__ x,
                                  const float* __restrict__ z,
                                  const float* __restrict__ borders,
                                  const float* __restrict__ inv_len,
                                  float2* __restrict__ xc,   // [32*512]
                                  uint2* __restrict__ zc2,   // [512][32]
                                  float* __restrict__ out) {
    const int gid = blockIdx.x * blockDim.x + threadIdx.x;
    out[gid] = 0.f;
    int idx; float w;
    if (gid < IN_X * BATCH) {
        grid_coord(x[gid], borders, inv_len, idx, w);
        xc[gid] = make_float2(w, __int_as_float(idx * XSTR));
    } else {
        const int g = gid - IN_X * BATCH;   // g = j*512 + b
        const int j = g >> 9;
        const int b = g & (BATCH - 1);
        grid_coord(z[g], borders, inv_len, idx, w);
        zc2[b * IN_Z + j] = make_uint2(h2u(__float2half2_rn(w)),
                                       (unsigned)(idx * LDS_STR));
    }
}

__device__ __forceinline__ void gather_slice(const unsigned* __restrict__ S,
                                             const uint4* __restrict__ zp4,
                                             const __half2 wx2, const int xoff,
                                             float& ax, float& ay) {
    #pragma unroll 4
    for (int jj = 0; jj < 16; ++jj) {
        const uint4 q = zp4[jj];               // 2 j's per VMEM load
        {
            const int base = xoff + (int)q.y + 2 * jj;
            const __half2 wz2 = u2h(q.x);
            const __half2 a0 = u2h(S[base]);
            const __half2 a1 = u2h(S[base + LDS_STR]);      // ds_read2 pair
            const __half2 b0 = u2h(S[base + XSTR]);
            const __half2 b1 = u2h(S[base + XSTR + LDS_STR]);
            const __half2 lo = __hfma2(wz2, __hsub2(a1, a0), a0);
            const __half2 hi = __hfma2(wz2, __hsub2(b1, b0), b0);
            const __half2 r  = __hfma2(wx2, __hsub2(hi, lo), lo);
            const float2 f = __half22float2(r);
            ax += f.x; ay += f.y;
        }
        {
            const int base = xoff + (int)q.w + 2 * jj + 1;
            const __half2 wz2 = u2h(q.z);
            const __half2 a0 = u2h(S[base]);
            const __half2 a1 = u2h(S[base + LDS_STR]);
            const __half2 b0 = u2h(S[base + XSTR]);
            const __half2 b1 = u2h(S[base + XSTR + LDS_STR]);
            const __half2 lo = __hfma2(wz2, __hsub2(a1, a0), a0);
            const __half2 hi = __hfma2(wz2, __hsub2(b1, b0), b0);
            const __half2 r  = __hfma2(wx2, __hsub2(hi, lo), lo);
            const float2 f = __half22float2(r);
            ax += f.x; ay += f.y;
        }
    }
}

__global__ __launch_bounds__(512, 4)
void bf2d_kernel(const float2* __restrict__ xc,
                 const uint2* __restrict__ zc2,
                 const float* __restrict__ P,
                 float* __restrict__ out) {
    __shared__ unsigned ldsA[CELLS * LDS_STR];   // 38148 B
    __shared__ unsigned ldsB[CELLS * LDS_STR];   // 38148 B

    const int tid = threadIdx.x;                 // batch element
    const int o0  = (blockIdx.x >> 4) * 2;       // o-pair
    const int i0  = (blockIdx.x & 15) * 2;       // i-pair
    const int i1  = i0 + 1;

    // P[cell, o, i, j]: strides 65536 / 1024 / 32 / 1
    const float* Pb = P + (size_t)o0 * 1024;

    float4 r0[NITER], r1[NITER];

    // ---- load slice i0 into regs ----
    #pragma unroll
    for (int t = 0; t < NITER; ++t) {
        const int k = tid + t * 512;
        if (k < QT) {
            const int c = k >> 3, j4 = (k & 7) << 2;
            const float* g = Pb + (size_t)c * 65536 + i0 * 32 + j4;
            r0[t] = *(const float4*)g;
            r1[t] = *(const float4*)(g + 1024);
        }
    }
    // ---- pack + write A ----
    #pragma unroll
    for (int t = 0; t < NITER; ++t) {
        const int k = tid + t * 512;
        if (k < QT) {
            const int c = k >> 3, j4 = (k & 7) << 2;
            unsigned* d = &ldsA[c * LDS_STR + j4];
            d[0] = h2u(__floats2half2_rn(r0[t].x, r1[t].x));
            d[1] = h2u(__floats2half2_rn(r0[t].y, r1[t].y));
            d[2] = h2u(__floats2half2_rn(r0[t].z, r1[t].z));
            d[3] = h2u(__floats2half2_rn(r0[t].w, r1[t].w));
        }
    }
    __syncthreads();

    // ---- issue slice i1 loads (in flight during gather of A) ----
    #pragma unroll
    for (int t = 0; t < NITER; ++t) {
        const int k = tid + t * 512;
        if (k < QT) {
            const int c = k >> 3, j4 = (k & 7) << 2;
            const float* g = Pb + (size_t)c * 65536 + i1 * 32 + j4;
            r0[t] = *(const float4*)g;
            r1[t] = *(const float4*)(g + 1024);
        }
    }

    const uint4* zp4 = (const uint4*)(zc2 + (size_t)tid * IN_Z);
    float accx = 0.f, accy = 0.f;

    // ---- gather i0 from A ----
    {
        const float2 xcv = xc[i0 * BATCH + tid];
        gather_slice(ldsA, zp4, __float2half2_rn(xcv.x),
                     __float_as_int(xcv.y), accx, accy);
    }

    // ---- pack + write B ----
    #pragma unroll
    for (int t = 0; t < NITER; ++t) {
        const int k = tid + t * 512;
        if (k < QT) {
            const int c = k >> 3, j4 = (k & 7) << 2;
            unsigned* d = &ldsB[c * LDS_STR + j4];
            d[0] = h2u(__floats2half2_rn(r0[t].x, r1[t].x));
            d[1] = h2u(__floats2half2_rn(r0[t].y, r1[t].y));
            d[2] = h2u(__floats2half2_rn(r0[t].z, r1[t].z));
            d[3] = h2u(__floats2half2_rn(r0[t].w, r1[t].w));
        }
    }
    __syncthreads();

    // ---- gather i1 from B ----
    {
        const float2 xcv = xc[i1 * BATCH + tid];
        gather_slice(ldsB, zp4, __float2half2_rn(xcv.x),
                     __float_as_int(xcv.y), accx, accy);
    }

    atomicAdd(&out[o0 * BATCH + tid],       accx);
    atomicAdd(&out[(o0 + 1) * BATCH + tid], accy);
}

extern "C" void kernel_launch(void* const* d_in, const int* in_sizes, int n_in,
                              void* d_out, int out_size, void* d_ws, size_t ws_size,
                              hipStream_t stream) {
    const float* x       = (const float*)d_in[0];   // (32, 512)
    const float* z       = (const float*)d_in[1];   // (32, 512)
    const float* P       = (const float*)d_in[2];   // (17,17,64,32,32)
    const float* borders = (const float*)d_in[3];   // (17,)
    const float* inv_len = (const float*)d_in[4];   // (16,)
    float* out = (float*)d_out;                     // (64, 512) = 32768

    float2* xc  = (float2*)d_ws;                    // 16384 float2 = 128 KB
    uint2*  zc2 = (uint2*)(xc + IN_X * BATCH);      // 16384 uint2  = 128 KB

    precompute_kernel<<<dim3(128), dim3(256), 0, stream>>>(
        x, z, borders, inv_len, xc, zc2, out);

    bf2d_kernel<<<dim3((OUT_DIM / 2) * (IN_X / 2)), dim3(512), 0, stream>>>(
        xc, zc2, P, out);
}